// Round 5
// baseline (1009.484 us; speedup 1.0000x reference)
//
#include <hip/hip_runtime.h>
#include <math.h>

#define B_  4
#define N_  4096
#define D_  1024
#define H_  16
#define HD_ 64
#define M_  64
#define TD_ 3072
#define EPS_ 1e-6f

typedef __attribute__((ext_vector_type(8))) short short8;
typedef __attribute__((ext_vector_type(4))) float floatx4;
typedef unsigned int uint32;
typedef unsigned short ushort;

// Split two fp32 into packed hi-bf16 pair and lo-bf16 pair.
__device__ __forceinline__ void cvt2(float f0, float f1, uint32& hp, uint32& lp)
{
    uint32 b0 = __float_as_uint(f0), b1 = __float_as_uint(f1);
    hp = (b1 & 0xFFFF0000u) | (b0 >> 16);
    float l0 = f0 - __uint_as_float(b0 & 0xFFFF0000u);
    float l1 = f1 - __uint_as_float(b1 & 0xFFFF0000u);
    lp = (__float_as_uint(l1) & 0xFFFF0000u) | (__float_as_uint(l0) >> 16);
}

// ---------------------------------------------------------------------------
// fp32[n] -> hi bf16[n], lo bf16[n].  n multiple of 2048; 8 elems/thread.
// ---------------------------------------------------------------------------
__global__ __launch_bounds__(256) void split_kernel(
    const float* __restrict__ src, ushort* __restrict__ hi,
    ushort* __restrict__ lo, int n)
{
    size_t i = ((size_t)blockIdx.x * 256 + threadIdx.x) * 8;
    if (i >= (size_t)n) return;
    float4 f0 = *(const float4*)(src + i);
    float4 f1 = *(const float4*)(src + i + 4);
    uint4 h, l;
    cvt2(f0.x, f0.y, h.x, l.x); cvt2(f0.z, f0.w, h.y, l.y);
    cvt2(f1.x, f1.y, h.z, l.z); cvt2(f1.z, f1.w, h.w, l.w);
    *(uint4*)(hi + i) = h;
    *(uint4*)(lo + i) = l;
}

// ---------------------------------------------------------------------------
// zero kvb[65536] + ksum[1024] (contiguous): 65 blocks x 256 thr x 4 floats
// ---------------------------------------------------------------------------
__global__ __launch_bounds__(256) void zero_kernel(float* __restrict__ p)
{
    int i = (blockIdx.x * 256 + threadIdx.x) * 4;
    if (i < 66560) *(float4*)(p + i) = make_float4(0.f, 0.f, 0.f, 0.f);
}

// ---------------------------------------------------------------------------
// OLD 128x128 kernel — kept for the small-workspace tier-C proj GEMM.
// ---------------------------------------------------------------------------
#define LDSTR 40

__global__ __launch_bounds__(256, 2) void gemm_presplit_nt_bias(
    const ushort* __restrict__ Ah, const ushort* __restrict__ Al,
    const ushort* __restrict__ Bh, const ushort* __restrict__ Bl,
    const float* __restrict__ bias, float* __restrict__ C,
    int Nx, int Kx)
{
    __shared__ __align__(16) ushort AhiS[128*LDSTR], AloS[128*LDSTR];
    __shared__ __align__(16) ushort BhiS[128*LDSTR], BloS[128*LDSTR];

    const int t    = threadIdx.x;
    const int bm   = blockIdx.y * 128, bn = blockIdx.x * 128;
    const int lane = t & 63, wave = t >> 6;
    const int wm   = wave >> 1, wn = wave & 1;
    const int l16  = lane & 15, quad = lane >> 4;
    const int r    = t >> 1;
    const int ko   = (t & 1) * 16;

    floatx4 acc[4][4];
#pragma unroll
    for (int i = 0; i < 4; i++)
#pragma unroll
        for (int j = 0; j < 4; j++) acc[i][j] = (floatx4)0.f;

    const ushort* aph = Ah + (size_t)(bm + r) * Kx + ko;
    const ushort* apl = Al + (size_t)(bm + r) * Kx + ko;
    const ushort* bph = Bh + (size_t)(bn + r) * Kx + ko;
    const ushort* bpl = Bl + (size_t)(bn + r) * Kx + ko;

    for (int k0 = 0; k0 < Kx; k0 += 32) {
        uint4 vah0 = *(const uint4*)(aph + k0);
        uint4 vah1 = *(const uint4*)(aph + k0 + 8);
        uint4 val0 = *(const uint4*)(apl + k0);
        uint4 val1 = *(const uint4*)(apl + k0 + 8);
        uint4 vbh0 = *(const uint4*)(bph + k0);
        uint4 vbh1 = *(const uint4*)(bph + k0 + 8);
        uint4 vbl0 = *(const uint4*)(bpl + k0);
        uint4 vbl1 = *(const uint4*)(bpl + k0 + 8);

        __syncthreads();

        *(uint4*)&AhiS[r*LDSTR + ko]     = vah0;
        *(uint4*)&AhiS[r*LDSTR + ko + 8] = vah1;
        *(uint4*)&AloS[r*LDSTR + ko]     = val0;
        *(uint4*)&AloS[r*LDSTR + ko + 8] = val1;
        *(uint4*)&BhiS[r*LDSTR + ko]     = vbh0;
        *(uint4*)&BhiS[r*LDSTR + ko + 8] = vbh1;
        *(uint4*)&BloS[r*LDSTR + ko]     = vbl0;
        *(uint4*)&BloS[r*LDSTR + ko + 8] = vbl1;

        __syncthreads();

        short8 ah[4], al[4], bh[4], bl[4];
#pragma unroll
        for (int mi = 0; mi < 4; mi++) {
            int row = (wm*64 + mi*16 + l16) * LDSTR + quad*8;
            ah[mi] = *(const short8*)&AhiS[row];
            al[mi] = *(const short8*)&AloS[row];
        }
#pragma unroll
        for (int ni = 0; ni < 4; ni++) {
            int row = (wn*64 + ni*16 + l16) * LDSTR + quad*8;
            bh[ni] = *(const short8*)&BhiS[row];
            bl[ni] = *(const short8*)&BloS[row];
        }
#pragma unroll
        for (int mi = 0; mi < 4; mi++)
#pragma unroll
            for (int ni = 0; ni < 4; ni++) {
                floatx4 d = acc[mi][ni];
                d = __builtin_amdgcn_mfma_f32_16x16x32_bf16(ah[mi], bh[ni], d, 0, 0, 0);
                d = __builtin_amdgcn_mfma_f32_16x16x32_bf16(al[mi], bh[ni], d, 0, 0, 0);
                d = __builtin_amdgcn_mfma_f32_16x16x32_bf16(ah[mi], bl[ni], d, 0, 0, 0);
                acc[mi][ni] = d;
            }
    }

    float bia[4];
#pragma unroll
    for (int ni = 0; ni < 4; ni++)
        bia[ni] = bias[bn + wn*64 + ni*16 + l16];
#pragma unroll
    for (int mi = 0; mi < 4; mi++)
#pragma unroll
        for (int rr = 0; rr < 4; rr++) {
            int row = bm + wm*64 + mi*16 + quad*4 + rr;
            float* crow = C + (size_t)row * Nx + bn + wn*64 + l16;
#pragma unroll
            for (int ni = 0; ni < 4; ni++)
                crow[ni*16] = acc[mi][ni][rr] + bia[ni];
        }
}

// ---------------------------------------------------------------------------
// 256x256 split-bf16 GEMM (NT) — round-2 measured-best schedule (84.6us,
// MfmaUtil 51%): operand-dedup (24 unique ds_read_b128 + 96 MFMA per K-tile
// per wave, 2 clusters), staging split A@tile-start / B@mid-tile, explicit
// lgkmcnt(0)+sched_barrier fences around MFMA clusters, vmcnt(0) tail.
// LDS 128 KiB double-buffered, XOR-swizzled -> conflict-free.
// ---------------------------------------------------------------------------
__device__ __forceinline__ void gload16(const void* g, void* l)
{
    __builtin_amdgcn_global_load_lds(
        (const __attribute__((address_space(1))) unsigned int*)g,
        (__attribute__((address_space(3))) unsigned int*)l,
        16, 0, 0);
}

#define BAR()  asm volatile("s_barrier" ::: "memory")
#define SBAR() __builtin_amdgcn_sched_barrier(0)

__global__ __launch_bounds__(512, 2) void gemm256_pipe(
    const ushort* __restrict__ Ah, const ushort* __restrict__ Al,
    const ushort* __restrict__ Bh, const ushort* __restrict__ Bl,
    const float* __restrict__ bias, float* __restrict__ C,
    int Nx, int Kx)
{
    __shared__ __align__(16) ushort lds[65536];   // 128 KiB

    const int t    = threadIdx.x;
    const int wave = t >> 6, lane = t & 63;
    const int wm   = wave >> 2, wn = wave & 3;     // 2 x 4 waves
    const int l16  = lane & 15, quad = lane >> 4;

    // XCD-aware block swizzle (all grids have nwg % 8 == 0)
    const int gx  = gridDim.x;
    const int nwg = gx * gridDim.y;
    int bid = blockIdx.y * gx + blockIdx.x;
    const int cpx = nwg >> 3;
    bid = (bid & 7) * cpx + (bid >> 3);
    const int bm = (bid / gx) * 256;
    const int bn = (bid % gx) * 256;

    // staging: thread t covers dest bytes [t*16, t*16+16) of an 8KB half;
    // row-in-half = t>>2; source column pre-swizzled (inverse of read swz)
    const int r0   = t >> 2;
    const int cswz = ((((t & 3) << 4) ^ ((t & 0x18) << 1)) >> 1);  // ushort col
    const size_t aOff = (size_t)(bm + r0) * Kx + cswz;
    const size_t bOff = (size_t)(bn + r0) * Kx + cswz;

    // fragment-read bases (ushort indices); swizzle folded into const ucol
    const int ucol = (quad * 8) ^ ((l16 & 6) << 2);
    const int aRB  = (wm * 64 + l16) * 32 + ucol;
    const int bRB  = (wn * 32 + l16) * 32 + ucol;

    floatx4 acc[8][4];
#pragma unroll
    for (int i = 0; i < 8; i++)
#pragma unroll
        for (int j = 0; j < 4; j++) acc[i][j] = (floatx4)0.f;

    // sub-buffer layout (ushort idx): buf*32768 + {Ah:0, Al:8192, Bh:16384,
    // Bl:24576} + half*4096 + row-in-half*32
#define STAGE_A2(NB, KT) do {                                                 \
    size_t g0_ = (size_t)(KT) * 32;                                           \
    gload16(Ah + aOff + g0_,                   &lds[(NB) + wave*512]);        \
    gload16(Al + aOff + g0_,                   &lds[(NB) + 8192 + wave*512]); \
    gload16(Ah + aOff + (size_t)128*Kx + g0_,  &lds[(NB) + 4096 + wave*512]); \
    gload16(Al + aOff + (size_t)128*Kx + g0_,  &lds[(NB) + 12288 + wave*512]);\
} while (0)
#define STAGE_B2(NB, KT) do {                                                 \
    size_t g0_ = (size_t)(KT) * 32;                                           \
    gload16(Bh + bOff + g0_,                   &lds[(NB) + 16384 + wave*512]);\
    gload16(Bl + bOff + g0_,                   &lds[(NB) + 24576 + wave*512]);\
    gload16(Bh + bOff + (size_t)128*Kx + g0_,  &lds[(NB) + 20480 + wave*512]);\
    gload16(Bl + bOff + (size_t)128*Kx + g0_,  &lds[(NB) + 28672 + wave*512]);\
} while (0)

    const int NT = Kx >> 5;   // K-tiles (32 for K=1024)

    // prologue: stage tile0 -> buf0
    STAGE_A2(0, 0);
    STAGE_B2(0, 0);
    asm volatile("s_waitcnt vmcnt(0)" ::: "memory");
    BAR();

    for (int kt = 0; kt < NT; kt++) {
        const int cb  = (kt & 1) << 15;       // current buffer base
        const int nb  = cb ^ 32768;           // next buffer base
        const int ktn = (kt + 1 < NT) ? kt + 1 : NT - 1;

        short8 ah_[4], al_[4], bh_[4], bl_[4];
        const int aB0 = cb + aRB;
        const int bB0 = cb + 16384 + bRB;

        // issue next-tile A staging early (max lookahead)
        STAGE_A2(nb, ktn);

        // read B (all 4 frag-pairs, held through both clusters) + A half 0
#pragma unroll
        for (int g = 0; g < 4; g++) {
            bh_[g] = *(const short8*)&lds[bB0 + (g >> 1)*4096 + (g & 1)*512];
            bl_[g] = *(const short8*)&lds[bB0 + 8192 + (g >> 1)*4096 + (g & 1)*512];
        }
#pragma unroll
        for (int mi = 0; mi < 4; mi++) {
            ah_[mi] = *(const short8*)&lds[aB0 + mi*512];
            al_[mi] = *(const short8*)&lds[aB0 + 8192 + mi*512];
        }
        asm volatile("s_waitcnt lgkmcnt(0)" ::: "memory");
        SBAR();
        __builtin_amdgcn_s_setprio(1);
#pragma unroll
        for (int mi = 0; mi < 4; mi++)
#pragma unroll
            for (int g = 0; g < 4; g++) {
                floatx4 d = acc[mi][g];
                d = __builtin_amdgcn_mfma_f32_16x16x32_bf16(ah_[mi], bh_[g], d, 0, 0, 0);
                d = __builtin_amdgcn_mfma_f32_16x16x32_bf16(al_[mi], bh_[g], d, 0, 0, 0);
                d = __builtin_amdgcn_mfma_f32_16x16x32_bf16(ah_[mi], bl_[g], d, 0, 0, 0);
                acc[mi][g] = d;
            }
        __builtin_amdgcn_s_setprio(0);
        SBAR();

        // issue next-tile B staging, read A half 1 (reuse regs)
        STAGE_B2(nb, ktn);
#pragma unroll
        for (int mi = 0; mi < 4; mi++) {
            ah_[mi] = *(const short8*)&lds[aB0 + 4096 + mi*512];
            al_[mi] = *(const short8*)&lds[aB0 + 12288 + mi*512];
        }
        asm volatile("s_waitcnt lgkmcnt(0)" ::: "memory");
        SBAR();
        __builtin_amdgcn_s_setprio(1);
#pragma unroll
        for (int mi = 0; mi < 4; mi++)
#pragma unroll
            for (int g = 0; g < 4; g++) {
                floatx4 d = acc[4 + mi][g];
                d = __builtin_amdgcn_mfma_f32_16x16x32_bf16(ah_[mi], bh_[g], d, 0, 0, 0);
                d = __builtin_amdgcn_mfma_f32_16x16x32_bf16(al_[mi], bh_[g], d, 0, 0, 0);
                d = __builtin_amdgcn_mfma_f32_16x16x32_bf16(ah_[mi], bl_[g], d, 0, 0, 0);
                acc[4 + mi][g] = d;
            }
        __builtin_amdgcn_s_setprio(0);
        SBAR();

        // next tile fully staged (issued ~1 tile ago -> latency covered);
        // barrier protects buf cb from tile kt+2 staging
        asm volatile("s_waitcnt vmcnt(0)" ::: "memory");
        BAR();
    }

    // epilogue
#pragma unroll
    for (int f = 0; f < 8; f++) {
        const int row = bm + (f >> 2)*128 + wm*64 + (f & 3)*16 + quad*4;
#pragma unroll
        for (int g = 0; g < 4; g++) {
            const int col = bn + (g >> 1)*128 + wn*32 + (g & 1)*16 + l16;
            const float bb = bias[col];
#pragma unroll
            for (int rr = 0; rr < 4; rr++)
                C[(size_t)(row + rr) * Nx + col] = acc[f][g][rr] + bb;
        }
    }
#undef STAGE_A2
#undef STAGE_B2
}

// ---------------------------------------------------------------------------
// FUSED favor + kv for ONE batch:
// grid (16 heads, 32 chunks of 128 rows), 256 threads.
// Per block: (1) qp for its 128 rows -> global; (2) kp for its 128 rows ->
// LDS ONLY (no HBM round-trip); (3) kv/ksum partial over its rows from LDS
// kp + global v, atomicAdd into kvb[h][64][64] / ksum[h][64] (pre-zeroed).
// Replaces favor_features + kv_partial + kv_reduce (3 dispatches -> 1).
// ---------------------------------------------------------------------------
__global__ __launch_bounds__(256) void favor_kv_kernel(
    const float* __restrict__ qkvb, const float* __restrict__ proj,
    float* __restrict__ qp, float* __restrict__ kvb, float* __restrict__ ksum)
{
    __shared__ float  projT[64*64];   // [d][m]
    __shared__ float  kpL[128*64];    // [row][m]
    __shared__ float4 dnbuf[4][64];
    const int t = threadIdx.x, wave = t >> 6, lane = t & 63;
    const int h  = blockIdx.x;
    const int n0 = blockIdx.y * 128;

    for (int i = t; i < 4096; i += 256)
        projT[(i & 63) * 64 + (i >> 6)] = proj[i];
    __syncthreads();

#define FAVOR_ROWS(PART, EMIT)                                                \
    {                                                                         \
        const float* src = qkvb + (PART) * D_ + h * HD_ + lane;               \
        for (int iter = 0; iter < 8; iter++) {                                \
            const int n = n0 + iter * 16 + wave * 4;                          \
            float v0 = src[(size_t)(n+0) * TD_];                              \
            float v1 = src[(size_t)(n+1) * TD_];                              \
            float v2 = src[(size_t)(n+2) * TD_];                              \
            float v3 = src[(size_t)(n+3) * TD_];                              \
            float4 dn = make_float4(v0*0.125f, v1*0.125f, v2*0.125f, v3*0.125f); \
            dnbuf[wave][lane] = dn;                                           \
            float s0 = dn.x*dn.x, s1 = dn.y*dn.y, s2 = dn.z*dn.z, s3 = dn.w*dn.w; \
            _Pragma("unroll")                                                 \
            for (int off = 32; off >= 1; off >>= 1) {                         \
                s0 += __shfl_xor(s0, off, 64);                                \
                s1 += __shfl_xor(s1, off, 64);                                \
                s2 += __shfl_xor(s2, off, 64);                                \
                s3 += __shfl_xor(s3, off, 64);                                \
            }                                                                 \
            float c0 = -0.5f*s0, c1 = -0.5f*s1, c2 = -0.5f*s2, c3 = -0.5f*s3; \
            _Pragma("unroll")                                                 \
            for (int d = 0; d < 64; d++) {                                    \
                float p = projT[d*64 + lane];                                 \
                float4 q = dnbuf[wave][d];                                    \
                c0 = fmaf(q.x, p, c0);                                        \
                c1 = fmaf(q.y, p, c1);                                        \
                c2 = fmaf(q.z, p, c2);                                        \
                c3 = fmaf(q.w, p, c3);                                        \
            }                                                                 \
            float m0 = c0, m1 = c1, m2 = c2, m3 = c3;                         \
            _Pragma("unroll")                                                 \
            for (int off = 32; off >= 1; off >>= 1) {                         \
                m0 = fmaxf(m0, __shfl_xor(m0, off, 64));                      \
                m1 = fmaxf(m1, __shfl_xor(m1, off, 64));                      \
                m2 = fmaxf(m2, __shfl_xor(m2, off, 64));                      \
                m3 = fmaxf(m3, __shfl_xor(m3, off, 64));                      \
            }                                                                 \
            float r0 = expf(c0 - m0) * 0.125f + EPS_;                         \
            float r1 = expf(c1 - m1) * 0.125f + EPS_;                         \
            float r2 = expf(c2 - m2) * 0.125f + EPS_;                         \
            float r3 = expf(c3 - m3) * 0.125f + EPS_;                         \
            EMIT;                                                             \
        }                                                                     \
    }

    // part 0: qp -> global
    FAVOR_ROWS(0, {
        size_t orow = ((size_t)h * N_ + n) * 64 + lane;
        qp[orow]       = r0;
        qp[orow + 64]  = r1;
        qp[orow + 128] = r2;
        qp[orow + 192] = r3;
    });

    // part 1: kp -> LDS only
    FAVOR_ROWS(1, {
        int lr = (n - n0) * 64 + lane;
        kpL[lr]       = r0;
        kpL[lr + 64]  = r1;
        kpL[lr + 128] = r2;
        kpL[lr + 192] = r3;
    });
#undef FAVOR_ROWS
    __syncthreads();

    // kv / ksum partial from LDS kp + global v, then atomics
    const int m0 = (t & 15) * 4;
    const int v0 = (t >> 4) * 4;
    const float* vsrc = qkvb + (size_t)n0 * TD_ + 2 * D_ + h * HD_ + v0;

    float acc[4][4];
#pragma unroll
    for (int i = 0; i < 4; i++)
#pragma unroll
        for (int j = 0; j < 4; j++) acc[i][j] = 0.f;
    float ks[4] = {0.f, 0.f, 0.f, 0.f};

#pragma unroll 4
    for (int n = 0; n < 128; n++) {
        float4 kq = *(const float4*)&kpL[n * 64 + m0];
        float4 vq = *(const float4*)(vsrc + (size_t)n * TD_);
        acc[0][0] = fmaf(kq.x, vq.x, acc[0][0]);
        acc[0][1] = fmaf(kq.x, vq.y, acc[0][1]);
        acc[0][2] = fmaf(kq.x, vq.z, acc[0][2]);
        acc[0][3] = fmaf(kq.x, vq.w, acc[0][3]);
        acc[1][0] = fmaf(kq.y, vq.x, acc[1][0]);
        acc[1][1] = fmaf(kq.y, vq.y, acc[1][1]);
        acc[1][2] = fmaf(kq.y, vq.z, acc[1][2]);
        acc[1][3] = fmaf(kq.y, vq.w, acc[1][3]);
        acc[2][0] = fmaf(kq.z, vq.x, acc[2][0]);
        acc[2][1] = fmaf(kq.z, vq.y, acc[2][1]);
        acc[2][2] = fmaf(kq.z, vq.z, acc[2][2]);
        acc[2][3] = fmaf(kq.z, vq.w, acc[2][3]);
        acc[3][0] = fmaf(kq.w, vq.x, acc[3][0]);
        acc[3][1] = fmaf(kq.w, vq.y, acc[3][1]);
        acc[3][2] = fmaf(kq.w, vq.z, acc[3][2]);
        acc[3][3] = fmaf(kq.w, vq.w, acc[3][3]);
        if (v0 == 0) {
            ks[0] += kq.x; ks[1] += kq.y; ks[2] += kq.z; ks[3] += kq.w;
        }
    }

    float* kvp = kvb + (size_t)h * 4096 + m0 * 64 + v0;
#pragma unroll
    for (int i = 0; i < 4; i++)
#pragma unroll
        for (int j = 0; j < 4; j++)
            atomicAdd(kvp + i * 64 + j, acc[i][j]);

    if (v0 == 0) {
#pragma unroll
        for (int i = 0; i < 4; i++)
            atomicAdd(ksum + h * 64 + m0 + i, ks[i]);
    }
}

// ---------------------------------------------------------------------------
// out[h,n,v] = (sum_m qp*kv) / (sum_m qp*ksum + eps) -> hi/lo bf16
// ---------------------------------------------------------------------------
__global__ __launch_bounds__(256) void out_kernel(
    const float* __restrict__ qp, const float* __restrict__ kv,
    const float* __restrict__ ksum, ushort* __restrict__ attn_hi,
    ushort* __restrict__ attn_lo)
{
    __shared__ float  kvs[4096];
    __shared__ float  kss[64];
    __shared__ float4 qbuf[4][64];
    const int t = threadIdx.x, lane = t & 63, wave = t >> 6;
    const int h = blockIdx.x;
    const int n0 = blockIdx.y * 64;

    for (int i = t; i < 4096; i += 256) kvs[i] = kv[(size_t)h * 4096 + i];
    if (t < 64) kss[t] = ksum[h * 64 + t];
    __syncthreads();

    const float* qsrc = qp + (size_t)h * N_ * 64 + lane;
    const size_t dbase = h * HD_ + lane;

    for (int iter = 0; iter < 4; iter++) {
        const int n = n0 + iter * 16 + wave * 4;
        float q0 = qsrc[(size_t)(n+0) * 64];
        float q1 = qsrc[(size_t)(n+1) * 64];
        float q2 = qsrc[(size_t)(n+2) * 64];
        float q3 = qsrc[(size_t)(n+3) * 64];
        qbuf[wave][lane] = make_float4(q0, q1, q2, q3);
        float t0 = q0 * kss[lane], t1 = q1 * kss[lane];
        float t2 = q2 * kss[lane], t3 = q3 * kss[lane];
#pragma unroll
        for (int off = 32; off >= 1; off >>= 1) {
            t0 += __shfl_xor(t0, off, 64);
            t1 += __shfl_xor(t1, off, 64);
            t2 += __shfl_xor(t2, off, 64);
            t3 += __shfl_xor(t3, off, 64);
        }
        float a0 = 0.f, a1 = 0.f, a2 = 0.f, a3 = 0.f;
#pragma unroll
        for (int m = 0; m < 64; m++) {
            float kvv = kvs[m*64 + lane];
            float4 q = qbuf[wave][m];
            a0 = fmaf(q.x, kvv, a0);
            a1 = fmaf(q.y, kvv, a1);
            a2 = fmaf(q.z, kvv, a2);
            a3 = fmaf(q.w, kvv, a3);
        }
        float r[4];
        r[0] = a0 / (t0 + EPS_); r[1] = a1 / (t1 + EPS_);
        r[2] = a2 / (t2 + EPS_); r[3] = a3 / (t3 + EPS_);
#pragma unroll
        for (int i = 0; i < 4; i++) {
            uint32 bits = __float_as_uint(r[i]);
            float lof = r[i] - __uint_as_float(bits & 0xFFFF0000u);
            size_t idx = (size_t)(n + i) * D_ + dbase;
            attn_hi[idx] = (ushort)(bits >> 16);
            attn_lo[idx] = (ushort)(__float_as_uint(lof) >> 16);
        }
    }
}

// ---------------------------------------------------------------------------
extern "C" void kernel_launch(void* const* d_in, const int* in_sizes, int n_in,
                              void* d_out, int out_size, void* d_ws, size_t ws_size,
                              hipStream_t stream)
{
    const float* x      = (const float*)d_in[0];   // [4,4096,1024]
    const float* qkv_w  = (const float*)d_in[1];   // [3072,1024]
    const float* qkv_b  = (const float*)d_in[2];   // [3072]
    const float* proj_w = (const float*)d_in[3];   // [1024,1024]
    const float* proj_b = (const float*)d_in[4];   // [1024]
    const float* pm     = (const float*)d_in[5];   // [64,64]
    float* out = (float*)d_out;                    // [4,4096,1024] fp32
    float* ws  = (float*)d_ws;

    const bool tierA = ws_size >= 327553024ULL;   // batched QKV + batched proj
    const bool tierB = ws_size >= 176558080ULL;   // per-batch QKV + batched proj

    if (tierA) {
        float* qkvbA  = ws;                          // 50,331,648 f
        float* qp     = qkvbA + 50331648;            //  4,194,304 f
        float* kp     = qp + 4194304;                //  4,194,304 f (unused now)
        float* kvb    = kp + 4194304;                //     65,536 f
        float* ksum   = kvb + 65536;                 //      1,024 f
        float* kvpart = ksum + 1024;                 //  2,097,152 f (unused now)
        float* kspart = kvpart + 2097152;            //     32,768 f (unused now)
        float* axw    = kspart + 32768;              // 16,777,216 f (xw then attn)
        float* wsplit = axw + 16777216;              //  4,194,304 f

        ushort* xw_hi    = (ushort*)axw;
        ushort* xw_lo    = xw_hi + 16777216;
        ushort* attn_hi  = xw_hi;                    // alias: xw dead after GEMM1
        ushort* attn_lo  = xw_lo;
        ushort* qkvw_hi  = (ushort*)wsplit;
        ushort* qkvw_lo  = qkvw_hi + 3145728;
        ushort* projw_hi = qkvw_lo + 3145728;
        ushort* projw_lo = projw_hi + 1048576;

        split_kernel<<<1536, 256, 0, stream>>>(qkv_w, qkvw_hi, qkvw_lo, TD_*D_);
        split_kernel<<<512,  256, 0, stream>>>(proj_w, projw_hi, projw_lo, D_*D_);
        split_kernel<<<8192, 256, 0, stream>>>(x, xw_hi, xw_lo, B_*N_*D_);

        gemm256_pipe<<<dim3(12, 64), 512, 0, stream>>>(
            xw_hi, xw_lo, qkvw_hi, qkvw_lo, qkv_b, qkvbA, TD_, D_);

        for (int b = 0; b < B_; b++) {
            const float* qkvb = qkvbA + (size_t)b * N_ * TD_;
            zero_kernel<<<65, 256, 0, stream>>>(kvb);
            favor_kv_kernel<<<dim3(16, 32), 256, 0, stream>>>(
                qkvb, pm, qp, kvb, ksum);
            out_kernel<<<dim3(16, 64), 256, 0, stream>>>(qp, kvb, ksum,
                attn_hi + (size_t)b * N_ * D_, attn_lo + (size_t)b * N_ * D_);
        }

        gemm256_pipe<<<dim3(4, 64), 512, 0, stream>>>(
            attn_hi, attn_lo, projw_hi, projw_lo, proj_b, out, D_, D_);
    } else if (tierB) {
        // per-batch QKV GEMM, batched proj GEMM (dedicated attnA)
        float* qkvb   = ws;                        // 12,582,912 f
        float* qp     = ws + 12582912;             //  4,194,304 f  (xw aliases)
        float* kp     = qp + 4194304;              //  4,194,304 f (unused now)
        float* kvb    = kp + 4194304;              //     65,536 f
        float* ksum   = kvb + 65536;               //      1,024 f
        float* kvpart = ksum + 1024;               //  2,097,152 f (unused now)
        float* kspart = kvpart + 2097152;          //     32,768 f (unused now)
        float* wsplit = kspart + 32768;            //  4,194,304 f
        float* attnA  = wsplit + 4194304;          // 16,777,216 f (64 MB)

        ushort* xw_hi    = (ushort*)qp;            // 16 MB inside qp region
        ushort* xw_lo    = xw_hi + 4194304;
        ushort* qkvw_hi  = (ushort*)wsplit;
        ushort* qkvw_lo  = qkvw_hi + 3145728;
        ushort* projw_hi = qkvw_lo + 3145728;
        ushort* projw_lo = projw_hi + 1048576;
        ushort* attnA_hi = (ushort*)attnA;         // [16384 x 1024]
        ushort* attnA_lo = attnA_hi + 16777216;

        split_kernel<<<1536, 256, 0, stream>>>(qkv_w, qkvw_hi, qkvw_lo, TD_*D_);
        split_kernel<<<512,  256, 0, stream>>>(proj_w, projw_hi, projw_lo, D_*D_);

        for (int b = 0; b < B_; b++) {
            const float* xb = x + (size_t)b * N_ * D_;
            split_kernel<<<2048, 256, 0, stream>>>(xb, xw_hi, xw_lo, N_*D_);
            gemm256_pipe<<<dim3(12, 16), 512, 0, stream>>>(
                xw_hi, xw_lo, qkvw_hi, qkvw_lo, qkv_b, qkvb, TD_, D_);
            zero_kernel<<<65, 256, 0, stream>>>(kvb);
            favor_kv_kernel<<<dim3(16, 32), 256, 0, stream>>>(
                qkvb, pm, qp, kvb, ksum);
            out_kernel<<<dim3(16, 64), 256, 0, stream>>>(qp, kvb, ksum,
                attnA_hi + (size_t)b * N_ * D_, attnA_lo + (size_t)b * N_ * D_);
        }

        gemm256_pipe<<<dim3(4, 64), 512, 0, stream>>>(
            attnA_hi, attnA_lo, projw_hi, projw_lo, proj_b, out, D_, D_);
    } else {
        // tier C: per-batch everything (~109.5 MB)
        float* qkvb   = ws;                        // 12,582,912 f
        float* qpreg  = ws + 12582912;             // 4,194,304 f
        float* kpreg  = qpreg + 4194304;           // 4,194,304 f
        float* kvb    = kpreg + 4194304;           // 65,536
        float* ksum   = kvb + 65536;               // 1,024
        float* kvpart = ksum + 1024;               // 2,097,152 (unused now)
        float* kspart = kvpart + 2097152;          // 32,768 (unused now)
        float* wsplit = kspart + 32768;            // 4,194,304 f

        ushort* xw_hi   = (ushort*)qpreg;
        ushort* xw_lo   = xw_hi + 4194304;
        float*  qp      = qpreg;
        ushort* attn_hi = (ushort*)kpreg;
        ushort* attn_lo = attn_hi + 4194304;
        ushort* qkvw_hi = (ushort*)wsplit;
        ushort* qkvw_lo = qkvw_hi + 3145728;
        ushort* projw_hi= qkvw_lo + 3145728;
        ushort* projw_lo= projw_hi + 1048576;

        split_kernel<<<TD_*D_/2048, 256, 0, stream>>>(qkv_w, qkvw_hi, qkvw_lo, TD_*D_);
        split_kernel<<<D_*D_/2048,  256, 0, stream>>>(proj_w, projw_hi, projw_lo, D_*D_);

        for (int b = 0; b < B_; b++) {
            const float* xb = x + (size_t)b * N_ * D_;
            float* outb = out + (size_t)b * N_ * D_;

            split_kernel<<<N_*D_/2048, 256, 0, stream>>>(xb, xw_hi, xw_lo, N_*D_);

            gemm256_pipe<<<dim3(12, 16), 512, 0, stream>>>(
                xw_hi, xw_lo, qkvw_hi, qkvw_lo, qkv_b, qkvb, TD_, D_);

            zero_kernel<<<65, 256, 0, stream>>>(kvb);
            favor_kv_kernel<<<dim3(16, 32), 256, 0, stream>>>(
                qkvb, pm, qp, kvb, ksum);

            out_kernel<<<dim3(16, 64), 256, 0, stream>>>(qp, kvb, ksum, attn_hi, attn_lo);

            dim3 g5(D_ / 128, N_ / 128);
            gemm_presplit_nt_bias<<<g5, 256, 0, stream>>>(
                attn_hi, attn_lo, projw_hi, projw_lo, proj_b, outb, D_, D_);
        }
    }
}

// Round 6
// 1005.224 us; speedup vs baseline: 1.0042x; 1.0042x over previous
//
#include <hip/hip_runtime.h>
#include <math.h>

#define B_  4
#define N_  4096
#define D_  1024
#define H_  16
#define HD_ 64
#define M_  64
#define TD_ 3072
#define EPS_ 1e-6f

typedef __attribute__((ext_vector_type(8))) short short8;
typedef __attribute__((ext_vector_type(4))) float floatx4;
typedef unsigned int uint32;
typedef unsigned short ushort;

// Split two fp32 into packed hi-bf16 pair and lo-bf16 pair.
__device__ __forceinline__ void cvt2(float f0, float f1, uint32& hp, uint32& lp)
{
    uint32 b0 = __float_as_uint(f0), b1 = __float_as_uint(f1);
    hp = (b1 & 0xFFFF0000u) | (b0 >> 16);
    float l0 = f0 - __uint_as_float(b0 & 0xFFFF0000u);
    float l1 = f1 - __uint_as_float(b1 & 0xFFFF0000u);
    lp = (__float_as_uint(l1) & 0xFFFF0000u) | (__float_as_uint(l0) >> 16);
}

// ---------------------------------------------------------------------------
// fp32[n] -> hi bf16[n], lo bf16[n].  n multiple of 2048; 8 elems/thread.
// ---------------------------------------------------------------------------
__global__ __launch_bounds__(256) void split_kernel(
    const float* __restrict__ src, ushort* __restrict__ hi,
    ushort* __restrict__ lo, int n)
{
    size_t i = ((size_t)blockIdx.x * 256 + threadIdx.x) * 8;
    if (i >= (size_t)n) return;
    float4 f0 = *(const float4*)(src + i);
    float4 f1 = *(const float4*)(src + i + 4);
    uint4 h, l;
    cvt2(f0.x, f0.y, h.x, l.x); cvt2(f0.z, f0.w, h.y, l.y);
    cvt2(f1.x, f1.y, h.z, l.z); cvt2(f1.z, f1.w, h.w, l.w);
    *(uint4*)(hi + i) = h;
    *(uint4*)(lo + i) = l;
}

// ---------------------------------------------------------------------------
// zero kvb[65536] + ksum[1024] (contiguous): 65 blocks x 256 thr x 4 floats
// ---------------------------------------------------------------------------
__global__ __launch_bounds__(256) void zero_kernel(float* __restrict__ p)
{
    int i = (blockIdx.x * 256 + threadIdx.x) * 4;
    if (i < 66560) *(float4*)(p + i) = make_float4(0.f, 0.f, 0.f, 0.f);
}

// ---------------------------------------------------------------------------
// OLD 128x128 kernel — kept for the small-workspace tier-C proj GEMM.
// ---------------------------------------------------------------------------
#define LDSTR 40

__global__ __launch_bounds__(256, 2) void gemm_presplit_nt_bias(
    const ushort* __restrict__ Ah, const ushort* __restrict__ Al,
    const ushort* __restrict__ Bh, const ushort* __restrict__ Bl,
    const float* __restrict__ bias, float* __restrict__ C,
    int Nx, int Kx)
{
    __shared__ __align__(16) ushort AhiS[128*LDSTR], AloS[128*LDSTR];
    __shared__ __align__(16) ushort BhiS[128*LDSTR], BloS[128*LDSTR];

    const int t    = threadIdx.x;
    const int bm   = blockIdx.y * 128, bn = blockIdx.x * 128;
    const int lane = t & 63, wave = t >> 6;
    const int wm   = wave >> 1, wn = wave & 1;
    const int l16  = lane & 15, quad = lane >> 4;
    const int r    = t >> 1;
    const int ko   = (t & 1) * 16;

    floatx4 acc[4][4];
#pragma unroll
    for (int i = 0; i < 4; i++)
#pragma unroll
        for (int j = 0; j < 4; j++) acc[i][j] = (floatx4)0.f;

    const ushort* aph = Ah + (size_t)(bm + r) * Kx + ko;
    const ushort* apl = Al + (size_t)(bm + r) * Kx + ko;
    const ushort* bph = Bh + (size_t)(bn + r) * Kx + ko;
    const ushort* bpl = Bl + (size_t)(bn + r) * Kx + ko;

    for (int k0 = 0; k0 < Kx; k0 += 32) {
        uint4 vah0 = *(const uint4*)(aph + k0);
        uint4 vah1 = *(const uint4*)(aph + k0 + 8);
        uint4 val0 = *(const uint4*)(apl + k0);
        uint4 val1 = *(const uint4*)(apl + k0 + 8);
        uint4 vbh0 = *(const uint4*)(bph + k0);
        uint4 vbh1 = *(const uint4*)(bph + k0 + 8);
        uint4 vbl0 = *(const uint4*)(bpl + k0);
        uint4 vbl1 = *(const uint4*)(bpl + k0 + 8);

        __syncthreads();

        *(uint4*)&AhiS[r*LDSTR + ko]     = vah0;
        *(uint4*)&AhiS[r*LDSTR + ko + 8] = vah1;
        *(uint4*)&AloS[r*LDSTR + ko]     = val0;
        *(uint4*)&AloS[r*LDSTR + ko + 8] = val1;
        *(uint4*)&BhiS[r*LDSTR + ko]     = vbh0;
        *(uint4*)&BhiS[r*LDSTR + ko + 8] = vbh1;
        *(uint4*)&BloS[r*LDSTR + ko]     = vbl0;
        *(uint4*)&BloS[r*LDSTR + ko + 8] = vbl1;

        __syncthreads();

        short8 ah[4], al[4], bh[4], bl[4];
#pragma unroll
        for (int mi = 0; mi < 4; mi++) {
            int row = (wm*64 + mi*16 + l16) * LDSTR + quad*8;
            ah[mi] = *(const short8*)&AhiS[row];
            al[mi] = *(const short8*)&AloS[row];
        }
#pragma unroll
        for (int ni = 0; ni < 4; ni++) {
            int row = (wn*64 + ni*16 + l16) * LDSTR + quad*8;
            bh[ni] = *(const short8*)&BhiS[row];
            bl[ni] = *(const short8*)&BloS[row];
        }
#pragma unroll
        for (int mi = 0; mi < 4; mi++)
#pragma unroll
            for (int ni = 0; ni < 4; ni++) {
                floatx4 d = acc[mi][ni];
                d = __builtin_amdgcn_mfma_f32_16x16x32_bf16(ah[mi], bh[ni], d, 0, 0, 0);
                d = __builtin_amdgcn_mfma_f32_16x16x32_bf16(al[mi], bh[ni], d, 0, 0, 0);
                d = __builtin_amdgcn_mfma_f32_16x16x32_bf16(ah[mi], bl[ni], d, 0, 0, 0);
                acc[mi][ni] = d;
            }
    }

    float bia[4];
#pragma unroll
    for (int ni = 0; ni < 4; ni++)
        bia[ni] = bias[bn + wn*64 + ni*16 + l16];
#pragma unroll
    for (int mi = 0; mi < 4; mi++)
#pragma unroll
        for (int rr = 0; rr < 4; rr++) {
            int row = bm + wm*64 + mi*16 + quad*4 + rr;
            float* crow = C + (size_t)row * Nx + bn + wn*64 + l16;
#pragma unroll
            for (int ni = 0; ni < 4; ni++)
                crow[ni*16] = acc[mi][ni][rr] + bia[ni];
        }
}

// ---------------------------------------------------------------------------
// 256x256 split-bf16 GEMM (NT) — round-2 measured-best schedule (84.6us,
// MfmaUtil 51%): operand-dedup (24 unique ds_read_b128 + 96 MFMA per K-tile
// per wave, 2 clusters), staging split A@tile-start / B@mid-tile, explicit
// lgkmcnt(0)+sched_barrier fences around MFMA clusters, vmcnt(0) tail.
// LDS 128 KiB double-buffered, XOR-swizzled -> conflict-free.
// ---------------------------------------------------------------------------
__device__ __forceinline__ void gload16(const void* g, void* l)
{
    __builtin_amdgcn_global_load_lds(
        (const __attribute__((address_space(1))) unsigned int*)g,
        (__attribute__((address_space(3))) unsigned int*)l,
        16, 0, 0);
}

#define BAR()  asm volatile("s_barrier" ::: "memory")
#define SBAR() __builtin_amdgcn_sched_barrier(0)

__global__ __launch_bounds__(512, 2) void gemm256_pipe(
    const ushort* __restrict__ Ah, const ushort* __restrict__ Al,
    const ushort* __restrict__ Bh, const ushort* __restrict__ Bl,
    const float* __restrict__ bias, float* __restrict__ C,
    int Nx, int Kx)
{
    __shared__ __align__(16) ushort lds[65536];   // 128 KiB

    const int t    = threadIdx.x;
    const int wave = t >> 6, lane = t & 63;
    const int wm   = wave >> 2, wn = wave & 3;     // 2 x 4 waves
    const int l16  = lane & 15, quad = lane >> 4;

    // XCD-aware block swizzle (all grids have nwg % 8 == 0)
    const int gx  = gridDim.x;
    const int nwg = gx * gridDim.y;
    int bid = blockIdx.y * gx + blockIdx.x;
    const int cpx = nwg >> 3;
    bid = (bid & 7) * cpx + (bid >> 3);
    const int bm = (bid / gx) * 256;
    const int bn = (bid % gx) * 256;

    // staging: thread t covers dest bytes [t*16, t*16+16) of an 8KB half;
    // row-in-half = t>>2; source column pre-swizzled (inverse of read swz)
    const int r0   = t >> 2;
    const int cswz = ((((t & 3) << 4) ^ ((t & 0x18) << 1)) >> 1);  // ushort col
    const size_t aOff = (size_t)(bm + r0) * Kx + cswz;
    const size_t bOff = (size_t)(bn + r0) * Kx + cswz;

    // fragment-read bases (ushort indices); swizzle folded into const ucol
    const int ucol = (quad * 8) ^ ((l16 & 6) << 2);
    const int aRB  = (wm * 64 + l16) * 32 + ucol;
    const int bRB  = (wn * 32 + l16) * 32 + ucol;

    floatx4 acc[8][4];
#pragma unroll
    for (int i = 0; i < 8; i++)
#pragma unroll
        for (int j = 0; j < 4; j++) acc[i][j] = (floatx4)0.f;

    // sub-buffer layout (ushort idx): buf*32768 + {Ah:0, Al:8192, Bh:16384,
    // Bl:24576} + half*4096 + row-in-half*32
#define STAGE_A2(NB, KT) do {                                                 \
    size_t g0_ = (size_t)(KT) * 32;                                           \
    gload16(Ah + aOff + g0_,                   &lds[(NB) + wave*512]);        \
    gload16(Al + aOff + g0_,                   &lds[(NB) + 8192 + wave*512]); \
    gload16(Ah + aOff + (size_t)128*Kx + g0_,  &lds[(NB) + 4096 + wave*512]); \
    gload16(Al + aOff + (size_t)128*Kx + g0_,  &lds[(NB) + 12288 + wave*512]);\
} while (0)
#define STAGE_B2(NB, KT) do {                                                 \
    size_t g0_ = (size_t)(KT) * 32;                                           \
    gload16(Bh + bOff + g0_,                   &lds[(NB) + 16384 + wave*512]);\
    gload16(Bl + bOff + g0_,                   &lds[(NB) + 24576 + wave*512]);\
    gload16(Bh + bOff + (size_t)128*Kx + g0_,  &lds[(NB) + 20480 + wave*512]);\
    gload16(Bl + bOff + (size_t)128*Kx + g0_,  &lds[(NB) + 28672 + wave*512]);\
} while (0)

    const int NT = Kx >> 5;   // K-tiles (32 for K=1024)

    // prologue: stage tile0 -> buf0
    STAGE_A2(0, 0);
    STAGE_B2(0, 0);
    asm volatile("s_waitcnt vmcnt(0)" ::: "memory");
    BAR();

    for (int kt = 0; kt < NT; kt++) {
        const int cb  = (kt & 1) << 15;       // current buffer base
        const int nb  = cb ^ 32768;           // next buffer base
        const int ktn = (kt + 1 < NT) ? kt + 1 : NT - 1;

        short8 ah_[4], al_[4], bh_[4], bl_[4];
        const int aB0 = cb + aRB;
        const int bB0 = cb + 16384 + bRB;

        // issue next-tile A staging early (max lookahead)
        STAGE_A2(nb, ktn);

        // read B (all 4 frag-pairs, held through both clusters) + A half 0
#pragma unroll
        for (int g = 0; g < 4; g++) {
            bh_[g] = *(const short8*)&lds[bB0 + (g >> 1)*4096 + (g & 1)*512];
            bl_[g] = *(const short8*)&lds[bB0 + 8192 + (g >> 1)*4096 + (g & 1)*512];
        }
#pragma unroll
        for (int mi = 0; mi < 4; mi++) {
            ah_[mi] = *(const short8*)&lds[aB0 + mi*512];
            al_[mi] = *(const short8*)&lds[aB0 + 8192 + mi*512];
        }
        asm volatile("s_waitcnt lgkmcnt(0)" ::: "memory");
        SBAR();
        __builtin_amdgcn_s_setprio(1);
#pragma unroll
        for (int mi = 0; mi < 4; mi++)
#pragma unroll
            for (int g = 0; g < 4; g++) {
                floatx4 d = acc[mi][g];
                d = __builtin_amdgcn_mfma_f32_16x16x32_bf16(ah_[mi], bh_[g], d, 0, 0, 0);
                d = __builtin_amdgcn_mfma_f32_16x16x32_bf16(al_[mi], bh_[g], d, 0, 0, 0);
                d = __builtin_amdgcn_mfma_f32_16x16x32_bf16(ah_[mi], bl_[g], d, 0, 0, 0);
                acc[mi][g] = d;
            }
        __builtin_amdgcn_s_setprio(0);
        SBAR();

        // issue next-tile B staging, read A half 1 (reuse regs)
        STAGE_B2(nb, ktn);
#pragma unroll
        for (int mi = 0; mi < 4; mi++) {
            ah_[mi] = *(const short8*)&lds[aB0 + 4096 + mi*512];
            al_[mi] = *(const short8*)&lds[aB0 + 12288 + mi*512];
        }
        asm volatile("s_waitcnt lgkmcnt(0)" ::: "memory");
        SBAR();
        __builtin_amdgcn_s_setprio(1);
#pragma unroll
        for (int mi = 0; mi < 4; mi++)
#pragma unroll
            for (int g = 0; g < 4; g++) {
                floatx4 d = acc[4 + mi][g];
                d = __builtin_amdgcn_mfma_f32_16x16x32_bf16(ah_[mi], bh_[g], d, 0, 0, 0);
                d = __builtin_amdgcn_mfma_f32_16x16x32_bf16(al_[mi], bh_[g], d, 0, 0, 0);
                d = __builtin_amdgcn_mfma_f32_16x16x32_bf16(ah_[mi], bl_[g], d, 0, 0, 0);
                acc[4 + mi][g] = d;
            }
        __builtin_amdgcn_s_setprio(0);
        SBAR();

        // next tile fully staged (issued ~1 tile ago -> latency covered);
        // barrier protects buf cb from tile kt+2 staging
        asm volatile("s_waitcnt vmcnt(0)" ::: "memory");
        BAR();
    }

    // epilogue
#pragma unroll
    for (int f = 0; f < 8; f++) {
        const int row = bm + (f >> 2)*128 + wm*64 + (f & 3)*16 + quad*4;
#pragma unroll
        for (int g = 0; g < 4; g++) {
            const int col = bn + (g >> 1)*128 + wn*32 + (g & 1)*16 + l16;
            const float bb = bias[col];
#pragma unroll
            for (int rr = 0; rr < 4; rr++)
                C[(size_t)(row + rr) * Nx + col] = acc[f][g][rr] + bb;
        }
    }
#undef STAGE_A2
#undef STAGE_B2
}

// ---------------------------------------------------------------------------
// FAVOR+ feature map for ONE batch (R4 version: 2048 blocks, 64 rows each).
// ---------------------------------------------------------------------------
__global__ __launch_bounds__(256) void favor_features_kernel(
    const float* __restrict__ qkvb, const float* __restrict__ proj,
    float* __restrict__ qp, float* __restrict__ kp)
{
    __shared__ float  projT[64*64];
    __shared__ float4 dnbuf[4][64];
    const int t = threadIdx.x;
    const int wave = t >> 6, lane = t & 63;
    const int part = blockIdx.y;
    float* outp = (part == 0) ? qp : kp;

    for (int i = t; i < 4096; i += 256)
        projT[(i & 63) * 64 + (i >> 6)] = proj[i];
    __syncthreads();

    const int h = blockIdx.x >> 6;
    const int n0 = (blockIdx.x & 63) * 64;
    const float* src = qkvb + part * D_ + h * HD_ + lane;

    for (int iter = 0; iter < 4; iter++) {
        const int n = n0 + iter * 16 + wave * 4;
        float v0 = src[(size_t)(n+0) * TD_];
        float v1 = src[(size_t)(n+1) * TD_];
        float v2 = src[(size_t)(n+2) * TD_];
        float v3 = src[(size_t)(n+3) * TD_];
        float4 dn = make_float4(v0*0.125f, v1*0.125f, v2*0.125f, v3*0.125f);
        dnbuf[wave][lane] = dn;
        float s0 = dn.x*dn.x, s1 = dn.y*dn.y, s2 = dn.z*dn.z, s3 = dn.w*dn.w;
#pragma unroll
        for (int off = 32; off >= 1; off >>= 1) {
            s0 += __shfl_xor(s0, off, 64);
            s1 += __shfl_xor(s1, off, 64);
            s2 += __shfl_xor(s2, off, 64);
            s3 += __shfl_xor(s3, off, 64);
        }
        float c0 = -0.5f*s0, c1 = -0.5f*s1, c2 = -0.5f*s2, c3 = -0.5f*s3;
#pragma unroll
        for (int d = 0; d < 64; d++) {
            float p = projT[d*64 + lane];
            float4 q = dnbuf[wave][d];
            c0 = fmaf(q.x, p, c0);
            c1 = fmaf(q.y, p, c1);
            c2 = fmaf(q.z, p, c2);
            c3 = fmaf(q.w, p, c3);
        }
        float m0 = c0, m1 = c1, m2 = c2, m3 = c3;
#pragma unroll
        for (int off = 32; off >= 1; off >>= 1) {
            m0 = fmaxf(m0, __shfl_xor(m0, off, 64));
            m1 = fmaxf(m1, __shfl_xor(m1, off, 64));
            m2 = fmaxf(m2, __shfl_xor(m2, off, 64));
            m3 = fmaxf(m3, __shfl_xor(m3, off, 64));
        }
        float r0 = expf(c0 - m0) * 0.125f + EPS_;
        float r1 = expf(c1 - m1) * 0.125f + EPS_;
        float r2 = expf(c2 - m2) * 0.125f + EPS_;
        float r3 = expf(c3 - m3) * 0.125f + EPS_;
        size_t orow = ((size_t)h * N_ + n) * 64 + lane;
        outp[orow]       = r0;
        outp[orow + 64]  = r1;
        outp[orow + 128] = r2;
        outp[orow + 192] = r3;
    }
}

// ---------------------------------------------------------------------------
// kv: per (h, n-chunk of 128) partial sums, atomicAdd into pre-zeroed
// kvb[h][64][64] / ksum[h][64].  Replaces kv_partial + kv_reduce (atomic
// path numerics-verified in round 5: absmax unchanged).
// ---------------------------------------------------------------------------
__global__ __launch_bounds__(256) void kv_partial_atomic(
    const float* __restrict__ qkvb, const float* __restrict__ kp,
    float* __restrict__ kvb, float* __restrict__ ksum)
{
    const int t = threadIdx.x;
    const int h = blockIdx.x;
    const int c = blockIdx.y;
    const int n0 = c * 128;
    const int m0 = (t & 15) * 4;
    const int v0 = (t >> 4) * 4;

    const float* kpsrc = kp + ((size_t)h * N_ + n0) * 64 + m0;
    const float* vsrc  = qkvb + (size_t)n0 * TD_ + 2 * D_ + h * HD_ + v0;

    float acc[4][4];
#pragma unroll
    for (int i = 0; i < 4; i++)
#pragma unroll
        for (int j = 0; j < 4; j++) acc[i][j] = 0.f;
    float ks[4] = {0.f, 0.f, 0.f, 0.f};

#pragma unroll 4
    for (int n = 0; n < 128; n++) {
        float4 kq = *(const float4*)(kpsrc + (size_t)n * 64);
        float4 vq = *(const float4*)(vsrc  + (size_t)n * TD_);
        acc[0][0] = fmaf(kq.x, vq.x, acc[0][0]);
        acc[0][1] = fmaf(kq.x, vq.y, acc[0][1]);
        acc[0][2] = fmaf(kq.x, vq.z, acc[0][2]);
        acc[0][3] = fmaf(kq.x, vq.w, acc[0][3]);
        acc[1][0] = fmaf(kq.y, vq.x, acc[1][0]);
        acc[1][1] = fmaf(kq.y, vq.y, acc[1][1]);
        acc[1][2] = fmaf(kq.y, vq.z, acc[1][2]);
        acc[1][3] = fmaf(kq.y, vq.w, acc[1][3]);
        acc[2][0] = fmaf(kq.z, vq.x, acc[2][0]);
        acc[2][1] = fmaf(kq.z, vq.y, acc[2][1]);
        acc[2][2] = fmaf(kq.z, vq.z, acc[2][2]);
        acc[2][3] = fmaf(kq.z, vq.w, acc[2][3]);
        acc[3][0] = fmaf(kq.w, vq.x, acc[3][0]);
        acc[3][1] = fmaf(kq.w, vq.y, acc[3][1]);
        acc[3][2] = fmaf(kq.w, vq.z, acc[3][2]);
        acc[3][3] = fmaf(kq.w, vq.w, acc[3][3]);
        if (v0 == 0) {
            ks[0] += kq.x; ks[1] += kq.y; ks[2] += kq.z; ks[3] += kq.w;
        }
    }

    float* kvp = kvb + (size_t)h * 4096 + m0 * 64 + v0;
#pragma unroll
    for (int i = 0; i < 4; i++)
#pragma unroll
        for (int j = 0; j < 4; j++)
            atomicAdd(kvp + i * 64 + j, acc[i][j]);

    if (v0 == 0) {
#pragma unroll
        for (int i = 0; i < 4; i++)
            atomicAdd(ksum + h * 64 + m0 + i, ks[i]);
    }
}

// ---------------------------------------------------------------------------
// out[h,n,v] = (sum_m qp*kv) / (sum_m qp*ksum + eps) -> hi/lo bf16
// ---------------------------------------------------------------------------
__global__ __launch_bounds__(256) void out_kernel(
    const float* __restrict__ qp, const float* __restrict__ kv,
    const float* __restrict__ ksum, ushort* __restrict__ attn_hi,
    ushort* __restrict__ attn_lo)
{
    __shared__ float  kvs[4096];
    __shared__ float  kss[64];
    __shared__ float4 qbuf[4][64];
    const int t = threadIdx.x, lane = t & 63, wave = t >> 6;
    const int h = blockIdx.x;
    const int n0 = blockIdx.y * 64;

    for (int i = t; i < 4096; i += 256) kvs[i] = kv[(size_t)h * 4096 + i];
    if (t < 64) kss[t] = ksum[h * 64 + t];
    __syncthreads();

    const float* qsrc = qp + (size_t)h * N_ * 64 + lane;
    const size_t dbase = h * HD_ + lane;

    for (int iter = 0; iter < 4; iter++) {
        const int n = n0 + iter * 16 + wave * 4;
        float q0 = qsrc[(size_t)(n+0) * 64];
        float q1 = qsrc[(size_t)(n+1) * 64];
        float q2 = qsrc[(size_t)(n+2) * 64];
        float q3 = qsrc[(size_t)(n+3) * 64];
        qbuf[wave][lane] = make_float4(q0, q1, q2, q3);
        float t0 = q0 * kss[lane], t1 = q1 * kss[lane];
        float t2 = q2 * kss[lane], t3 = q3 * kss[lane];
#pragma unroll
        for (int off = 32; off >= 1; off >>= 1) {
            t0 += __shfl_xor(t0, off, 64);
            t1 += __shfl_xor(t1, off, 64);
            t2 += __shfl_xor(t2, off, 64);
            t3 += __shfl_xor(t3, off, 64);
        }
        float a0 = 0.f, a1 = 0.f, a2 = 0.f, a3 = 0.f;
#pragma unroll
        for (int m = 0; m < 64; m++) {
            float kvv = kvs[m*64 + lane];
            float4 q = qbuf[wave][m];
            a0 = fmaf(q.x, kvv, a0);
            a1 = fmaf(q.y, kvv, a1);
            a2 = fmaf(q.z, kvv, a2);
            a3 = fmaf(q.w, kvv, a3);
        }
        float r[4];
        r[0] = a0 / (t0 + EPS_); r[1] = a1 / (t1 + EPS_);
        r[2] = a2 / (t2 + EPS_); r[3] = a3 / (t3 + EPS_);
#pragma unroll
        for (int i = 0; i < 4; i++) {
            uint32 bits = __float_as_uint(r[i]);
            float lof = r[i] - __uint_as_float(bits & 0xFFFF0000u);
            size_t idx = (size_t)(n + i) * D_ + dbase;
            attn_hi[idx] = (ushort)(bits >> 16);
            attn_lo[idx] = (ushort)(__float_as_uint(lof) >> 16);
        }
    }
}

// ---------------------------------------------------------------------------
extern "C" void kernel_launch(void* const* d_in, const int* in_sizes, int n_in,
                              void* d_out, int out_size, void* d_ws, size_t ws_size,
                              hipStream_t stream)
{
    const float* x      = (const float*)d_in[0];   // [4,4096,1024]
    const float* qkv_w  = (const float*)d_in[1];   // [3072,1024]
    const float* qkv_b  = (const float*)d_in[2];   // [3072]
    const float* proj_w = (const float*)d_in[3];   // [1024,1024]
    const float* proj_b = (const float*)d_in[4];   // [1024]
    const float* pm     = (const float*)d_in[5];   // [64,64]
    float* out = (float*)d_out;                    // [4,4096,1024] fp32
    float* ws  = (float*)d_ws;

    // tier A: batched QKV (768 blocks = 3 full CU rounds) + batched proj
    const bool tierA = ws_size >= 319033344ULL;
    // tier B: per-batch QKV + batched proj
    const bool tierB = ws_size >= 168038400ULL;

    if (tierA) {
        float* qkvbA  = ws;                          // 50,331,648 f
        float* qp     = qkvbA + 50331648;            //  4,194,304 f
        float* kp     = qp + 4194304;                //  4,194,304 f
        float* kvb    = kp + 4194304;                //     65,536 f
        float* ksum   = kvb + 65536;                 //      1,024 f
        float* axw    = ksum + 1024;                 // 16,777,216 f (xw then attn)
        float* wsplit = axw + 16777216;              //  4,194,304 f
        // total 79,758,336 f = 319,033,344 B

        ushort* xw_hi    = (ushort*)axw;
        ushort* xw_lo    = xw_hi + 16777216;
        ushort* attn_hi  = xw_hi;                    // alias: xw dead after GEMM1
        ushort* attn_lo  = xw_lo;
        ushort* qkvw_hi  = (ushort*)wsplit;
        ushort* qkvw_lo  = qkvw_hi + 3145728;
        ushort* projw_hi = qkvw_lo + 3145728;
        ushort* projw_lo = projw_hi + 1048576;

        split_kernel<<<1536, 256, 0, stream>>>(qkv_w, qkvw_hi, qkvw_lo, TD_*D_);
        split_kernel<<<512,  256, 0, stream>>>(proj_w, projw_hi, projw_lo, D_*D_);
        split_kernel<<<8192, 256, 0, stream>>>(x, xw_hi, xw_lo, B_*N_*D_);

        // all-batch QKV: [16384 x 3072], grid (12,64) = 768 = 3 full rounds
        gemm256_pipe<<<dim3(12, 64), 512, 0, stream>>>(
            xw_hi, xw_lo, qkvw_hi, qkvw_lo, qkv_b, qkvbA, TD_, D_);

        for (int b = 0; b < B_; b++) {
            const float* qkvb = qkvbA + (size_t)b * N_ * TD_;
            zero_kernel<<<65, 256, 0, stream>>>(kvb);
            favor_features_kernel<<<dim3(1024, 2), 256, 0, stream>>>(qkvb, pm, qp, kp);
            kv_partial_atomic<<<dim3(16, 32), 256, 0, stream>>>(qkvb, kp, kvb, ksum);
            out_kernel<<<dim3(16, 64), 256, 0, stream>>>(qp, kvb, ksum,
                attn_hi + (size_t)b * N_ * D_, attn_lo + (size_t)b * N_ * D_);
        }

        gemm256_pipe<<<dim3(4, 64), 512, 0, stream>>>(
            attn_hi, attn_lo, projw_hi, projw_lo, proj_b, out, D_, D_);
    } else if (tierB) {
        float* qkvb   = ws;                        // 12,582,912 f
        float* qp     = ws + 12582912;             //  4,194,304 f (xw aliases)
        float* kp     = qp + 4194304;              //  4,194,304 f
        float* kvb    = kp + 4194304;              //     65,536 f
        float* ksum   = kvb + 65536;               //      1,024 f
        float* wsplit = ksum + 1024;               //  4,194,304 f
        float* attnA  = wsplit + 4194304;          // 16,777,216 f
        // total 42,009,600 f = 168,038,400 B

        ushort* xw_hi    = (ushort*)qp;
        ushort* xw_lo    = xw_hi + 4194304;
        ushort* qkvw_hi  = (ushort*)wsplit;
        ushort* qkvw_lo  = qkvw_hi + 3145728;
        ushort* projw_hi = qkvw_lo + 3145728;
        ushort* projw_lo = projw_hi + 1048576;
        ushort* attnA_hi = (ushort*)attnA;         // [16384 x 1024]
        ushort* attnA_lo = attnA_hi + 16777216;

        split_kernel<<<1536, 256, 0, stream>>>(qkv_w, qkvw_hi, qkvw_lo, TD_*D_);
        split_kernel<<<512,  256, 0, stream>>>(proj_w, projw_hi, projw_lo, D_*D_);

        for (int b = 0; b < B_; b++) {
            const float* xb = x + (size_t)b * N_ * D_;
            split_kernel<<<2048, 256, 0, stream>>>(xb, xw_hi, xw_lo, N_*D_);
            gemm256_pipe<<<dim3(12, 16), 512, 0, stream>>>(
                xw_hi, xw_lo, qkvw_hi, qkvw_lo, qkv_b, qkvb, TD_, D_);
            zero_kernel<<<65, 256, 0, stream>>>(kvb);
            favor_features_kernel<<<dim3(1024, 2), 256, 0, stream>>>(qkvb, pm, qp, kp);
            kv_partial_atomic<<<dim3(16, 32), 256, 0, stream>>>(qkvb, kp, kvb, ksum);
            out_kernel<<<dim3(16, 64), 256, 0, stream>>>(qp, kvb, ksum,
                attnA_hi + (size_t)b * N_ * D_, attnA_lo + (size_t)b * N_ * D_);
        }

        gemm256_pipe<<<dim3(4, 64), 512, 0, stream>>>(
            attnA_hi, attnA_lo, projw_hi, projw_lo, proj_b, out, D_, D_);
    } else {
        // tier C: per-batch everything (~100.9 MB)
        float* qkvb   = ws;                        // 12,582,912 f
        float* qpreg  = ws + 12582912;             //  4,194,304 f
        float* kpreg  = qpreg + 4194304;           //  4,194,304 f
        float* kvb    = kpreg + 4194304;           //     65,536 f
        float* ksum   = kvb + 65536;               //      1,024 f
        float* wsplit = ksum + 1024;               //  4,194,304 f

        ushort* xw_hi   = (ushort*)qpreg;
        ushort* xw_lo   = xw_hi + 4194304;
        float*  qp      = qpreg;
        float*  kp      = kpreg;
        ushort* attn_hi = (ushort*)kpreg;          // kp dead before out writes
        ushort* attn_lo = attn_hi + 4194304;
        ushort* qkvw_hi = (ushort*)wsplit;
        ushort* qkvw_lo = qkvw_hi + 3145728;
        ushort* projw_hi= qkvw_lo + 3145728;
        ushort* projw_lo= projw_hi + 1048576;

        split_kernel<<<TD_*D_/2048, 256, 0, stream>>>(qkv_w, qkvw_hi, qkvw_lo, TD_*D_);
        split_kernel<<<D_*D_/2048,  256, 0, stream>>>(proj_w, projw_hi, projw_lo, D_*D_);

        for (int b = 0; b < B_; b++) {
            const float* xb = x + (size_t)b * N_ * D_;
            float* outb = out + (size_t)b * N_ * D_;

            split_kernel<<<N_*D_/2048, 256, 0, stream>>>(xb, xw_hi, xw_lo, N_*D_);

            gemm256_pipe<<<dim3(12, 16), 512, 0, stream>>>(
                xw_hi, xw_lo, qkvw_hi, qkvw_lo, qkv_b, qkvb, TD_, D_);

            zero_kernel<<<65, 256, 0, stream>>>(kvb);
            favor_features_kernel<<<dim3(1024, 2), 256, 0, stream>>>(qkvb, pm, qp, kp);
            kv_partial_atomic<<<dim3(16, 32), 256, 0, stream>>>(qkvb, kp, kvb, ksum);

            out_kernel<<<dim3(16, 64), 256, 0, stream>>>(qp, kvb, ksum, attn_hi, attn_lo);

            dim3 g5(D_ / 128, N_ / 128);
            gemm_presplit_nt_bias<<<g5, 256, 0, stream>>>(
                attn_hi, attn_lo, projw_hi, projw_lo, proj_b, outb, D_, D_);
        }
    }
}

// Round 9
// 943.871 us; speedup vs baseline: 1.0695x; 1.0650x over previous
//
#include <hip/hip_runtime.h>
#include <math.h>

#define B_  4
#define N_  4096
#define D_  1024
#define H_  16
#define HD_ 64
#define M_  64
#define TD_ 3072
#define EPS_ 1e-6f

typedef __attribute__((ext_vector_type(8))) short short8;
typedef __attribute__((ext_vector_type(4))) float floatx4;
typedef unsigned int uint32;
typedef unsigned short ushort;

// Split two fp32 into packed hi-bf16 pair and lo-bf16 pair.
__device__ __forceinline__ void cvt2(float f0, float f1, uint32& hp, uint32& lp)
{
    uint32 b0 = __float_as_uint(f0), b1 = __float_as_uint(f1);
    hp = (b1 & 0xFFFF0000u) | (b0 >> 16);
    float l0 = f0 - __uint_as_float(b0 & 0xFFFF0000u);
    float l1 = f1 - __uint_as_float(b1 & 0xFFFF0000u);
    lp = (__float_as_uint(l1) & 0xFFFF0000u) | (__float_as_uint(l0) >> 16);
}

// ---------------------------------------------------------------------------
// fp32[n] -> hi bf16[n], lo bf16[n].  n multiple of 2048; 8 elems/thread.
// ---------------------------------------------------------------------------
__global__ __launch_bounds__(256) void split_kernel(
    const float* __restrict__ src, ushort* __restrict__ hi,
    ushort* __restrict__ lo, int n)
{
    size_t i = ((size_t)blockIdx.x * 256 + threadIdx.x) * 8;
    if (i >= (size_t)n) return;
    float4 f0 = *(const float4*)(src + i);
    float4 f1 = *(const float4*)(src + i + 4);
    uint4 h, l;
    cvt2(f0.x, f0.y, h.x, l.x); cvt2(f0.z, f0.w, h.y, l.y);
    cvt2(f1.x, f1.y, h.z, l.z); cvt2(f1.z, f1.w, h.w, l.w);
    *(uint4*)(hi + i) = h;
    *(uint4*)(lo + i) = l;
}

// ---------------------------------------------------------------------------
// OLD 128x128 kernel — kept for the small-workspace tier-C proj GEMM.
// ---------------------------------------------------------------------------
#define LDSTR 40

__global__ __launch_bounds__(256, 2) void gemm_presplit_nt_bias(
    const ushort* __restrict__ Ah, const ushort* __restrict__ Al,
    const ushort* __restrict__ Bh, const ushort* __restrict__ Bl,
    const float* __restrict__ bias, float* __restrict__ C,
    int Nx, int Kx)
{
    __shared__ __align__(16) ushort AhiS[128*LDSTR], AloS[128*LDSTR];
    __shared__ __align__(16) ushort BhiS[128*LDSTR], BloS[128*LDSTR];

    const int t    = threadIdx.x;
    const int bm   = blockIdx.y * 128, bn = blockIdx.x * 128;
    const int lane = t & 63, wave = t >> 6;
    const int wm   = wave >> 1, wn = wave & 1;
    const int l16  = lane & 15, quad = lane >> 4;
    const int r    = t >> 1;
    const int ko   = (t & 1) * 16;

    floatx4 acc[4][4];
#pragma unroll
    for (int i = 0; i < 4; i++)
#pragma unroll
        for (int j = 0; j < 4; j++) acc[i][j] = (floatx4)0.f;

    const ushort* aph = Ah + (size_t)(bm + r) * Kx + ko;
    const ushort* apl = Al + (size_t)(bm + r) * Kx + ko;
    const ushort* bph = Bh + (size_t)(bn + r) * Kx + ko;
    const ushort* bpl = Bl + (size_t)(bn + r) * Kx + ko;

    for (int k0 = 0; k0 < Kx; k0 += 32) {
        uint4 vah0 = *(const uint4*)(aph + k0);
        uint4 vah1 = *(const uint4*)(aph + k0 + 8);
        uint4 val0 = *(const uint4*)(apl + k0);
        uint4 val1 = *(const uint4*)(apl + k0 + 8);
        uint4 vbh0 = *(const uint4*)(bph + k0);
        uint4 vbh1 = *(const uint4*)(bph + k0 + 8);
        uint4 vbl0 = *(const uint4*)(bpl + k0);
        uint4 vbl1 = *(const uint4*)(bpl + k0 + 8);

        __syncthreads();

        *(uint4*)&AhiS[r*LDSTR + ko]     = vah0;
        *(uint4*)&AhiS[r*LDSTR + ko + 8] = vah1;
        *(uint4*)&AloS[r*LDSTR + ko]     = val0;
        *(uint4*)&AloS[r*LDSTR + ko + 8] = val1;
        *(uint4*)&BhiS[r*LDSTR + ko]     = vbh0;
        *(uint4*)&BhiS[r*LDSTR + ko + 8] = vbh1;
        *(uint4*)&BloS[r*LDSTR + ko]     = vbl0;
        *(uint4*)&BloS[r*LDSTR + ko + 8] = vbl1;

        __syncthreads();

        short8 ah[4], al[4], bh[4], bl[4];
#pragma unroll
        for (int mi = 0; mi < 4; mi++) {
            int row = (wm*64 + mi*16 + l16) * LDSTR + quad*8;
            ah[mi] = *(const short8*)&AhiS[row];
            al[mi] = *(const short8*)&AloS[row];
        }
#pragma unroll
        for (int ni = 0; ni < 4; ni++) {
            int row = (wn*64 + ni*16 + l16) * LDSTR + quad*8;
            bh[ni] = *(const short8*)&BhiS[row];
            bl[ni] = *(const short8*)&BloS[row];
        }
#pragma unroll
        for (int mi = 0; mi < 4; mi++)
#pragma unroll
            for (int ni = 0; ni < 4; ni++) {
                floatx4 d = acc[mi][ni];
                d = __builtin_amdgcn_mfma_f32_16x16x32_bf16(ah[mi], bh[ni], d, 0, 0, 0);
                d = __builtin_amdgcn_mfma_f32_16x16x32_bf16(al[mi], bh[ni], d, 0, 0, 0);
                d = __builtin_amdgcn_mfma_f32_16x16x32_bf16(ah[mi], bl[ni], d, 0, 0, 0);
                acc[mi][ni] = d;
            }
    }

    float bia[4];
#pragma unroll
    for (int ni = 0; ni < 4; ni++)
        bia[ni] = bias[bn + wn*64 + ni*16 + l16];
#pragma unroll
    for (int mi = 0; mi < 4; mi++)
#pragma unroll
        for (int rr = 0; rr < 4; rr++) {
            int row = bm + wm*64 + mi*16 + quad*4 + rr;
            float* crow = C + (size_t)row * Nx + bn + wn*64 + l16;
#pragma unroll
            for (int ni = 0; ni < 4; ni++)
                crow[ni*16] = acc[mi][ni][rr] + bia[ni];
        }
}

// ---------------------------------------------------------------------------
// 256x256 split-bf16 GEMM (NT) — round-2 measured-best schedule (83us,
// MfmaUtil 51%; verified again round 6).
// ---------------------------------------------------------------------------
__device__ __forceinline__ void gload16(const void* g, void* l)
{
    __builtin_amdgcn_global_load_lds(
        (const __attribute__((address_space(1))) unsigned int*)g,
        (__attribute__((address_space(3))) unsigned int*)l,
        16, 0, 0);
}

#define BAR()  asm volatile("s_barrier" ::: "memory")
#define SBAR() __builtin_amdgcn_sched_barrier(0)

__global__ __launch_bounds__(512, 2) void gemm256_pipe(
    const ushort* __restrict__ Ah, const ushort* __restrict__ Al,
    const ushort* __restrict__ Bh, const ushort* __restrict__ Bl,
    const float* __restrict__ bias, float* __restrict__ C,
    int Nx, int Kx)
{
    __shared__ __align__(16) ushort lds[65536];   // 128 KiB

    const int t    = threadIdx.x;
    const int wave = t >> 6, lane = t & 63;
    const int wm   = wave >> 2, wn = wave & 3;     // 2 x 4 waves
    const int l16  = lane & 15, quad = lane >> 4;

    // XCD-aware block swizzle (all grids have nwg % 8 == 0)
    const int gx  = gridDim.x;
    const int nwg = gx * gridDim.y;
    int bid = blockIdx.y * gx + blockIdx.x;
    const int cpx = nwg >> 3;
    bid = (bid & 7) * cpx + (bid >> 3);
    const int bm = (bid / gx) * 256;
    const int bn = (bid % gx) * 256;

    const int r0   = t >> 2;
    const int cswz = ((((t & 3) << 4) ^ ((t & 0x18) << 1)) >> 1);  // ushort col
    const size_t aOff = (size_t)(bm + r0) * Kx + cswz;
    const size_t bOff = (size_t)(bn + r0) * Kx + cswz;

    const int ucol = (quad * 8) ^ ((l16 & 6) << 2);
    const int aRB  = (wm * 64 + l16) * 32 + ucol;
    const int bRB  = (wn * 32 + l16) * 32 + ucol;

    floatx4 acc[8][4];
#pragma unroll
    for (int i = 0; i < 8; i++)
#pragma unroll
        for (int j = 0; j < 4; j++) acc[i][j] = (floatx4)0.f;

#define STAGE_A2(NB, KT) do {                                                 \
    size_t g0_ = (size_t)(KT) * 32;                                           \
    gload16(Ah + aOff + g0_,                   &lds[(NB) + wave*512]);        \
    gload16(Al + aOff + g0_,                   &lds[(NB) + 8192 + wave*512]); \
    gload16(Ah + aOff + (size_t)128*Kx + g0_,  &lds[(NB) + 4096 + wave*512]); \
    gload16(Al + aOff + (size_t)128*Kx + g0_,  &lds[(NB) + 12288 + wave*512]);\
} while (0)
#define STAGE_B2(NB, KT) do {                                                 \
    size_t g0_ = (size_t)(KT) * 32;                                           \
    gload16(Bh + bOff + g0_,                   &lds[(NB) + 16384 + wave*512]);\
    gload16(Bl + bOff + g0_,                   &lds[(NB) + 24576 + wave*512]);\
    gload16(Bh + bOff + (size_t)128*Kx + g0_,  &lds[(NB) + 20480 + wave*512]);\
    gload16(Bl + bOff + (size_t)128*Kx + g0_,  &lds[(NB) + 28672 + wave*512]);\
} while (0)

    const int NT = Kx >> 5;

    STAGE_A2(0, 0);
    STAGE_B2(0, 0);
    asm volatile("s_waitcnt vmcnt(0)" ::: "memory");
    BAR();

    for (int kt = 0; kt < NT; kt++) {
        const int cb  = (kt & 1) << 15;
        const int nb  = cb ^ 32768;
        const int ktn = (kt + 1 < NT) ? kt + 1 : NT - 1;

        short8 ah_[4], al_[4], bh_[4], bl_[4];
        const int aB0 = cb + aRB;
        const int bB0 = cb + 16384 + bRB;

        STAGE_A2(nb, ktn);

#pragma unroll
        for (int g = 0; g < 4; g++) {
            bh_[g] = *(const short8*)&lds[bB0 + (g >> 1)*4096 + (g & 1)*512];
            bl_[g] = *(const short8*)&lds[bB0 + 8192 + (g >> 1)*4096 + (g & 1)*512];
        }
#pragma unroll
        for (int mi = 0; mi < 4; mi++) {
            ah_[mi] = *(const short8*)&lds[aB0 + mi*512];
            al_[mi] = *(const short8*)&lds[aB0 + 8192 + mi*512];
        }
        asm volatile("s_waitcnt lgkmcnt(0)" ::: "memory");
        SBAR();
        __builtin_amdgcn_s_setprio(1);
#pragma unroll
        for (int mi = 0; mi < 4; mi++)
#pragma unroll
            for (int g = 0; g < 4; g++) {
                floatx4 d = acc[mi][g];
                d = __builtin_amdgcn_mfma_f32_16x16x32_bf16(ah_[mi], bh_[g], d, 0, 0, 0);
                d = __builtin_amdgcn_mfma_f32_16x16x32_bf16(al_[mi], bh_[g], d, 0, 0, 0);
                d = __builtin_amdgcn_mfma_f32_16x16x32_bf16(ah_[mi], bl_[g], d, 0, 0, 0);
                acc[mi][g] = d;
            }
        __builtin_amdgcn_s_setprio(0);
        SBAR();

        STAGE_B2(nb, ktn);
#pragma unroll
        for (int mi = 0; mi < 4; mi++) {
            ah_[mi] = *(const short8*)&lds[aB0 + 4096 + mi*512];
            al_[mi] = *(const short8*)&lds[aB0 + 12288 + mi*512];
        }
        asm volatile("s_waitcnt lgkmcnt(0)" ::: "memory");
        SBAR();
        __builtin_amdgcn_s_setprio(1);
#pragma unroll
        for (int mi = 0; mi < 4; mi++)
#pragma unroll
            for (int g = 0; g < 4; g++) {
                floatx4 d = acc[4 + mi][g];
                d = __builtin_amdgcn_mfma_f32_16x16x32_bf16(ah_[mi], bh_[g], d, 0, 0, 0);
                d = __builtin_amdgcn_mfma_f32_16x16x32_bf16(al_[mi], bh_[g], d, 0, 0, 0);
                d = __builtin_amdgcn_mfma_f32_16x16x32_bf16(ah_[mi], bl_[g], d, 0, 0, 0);
                acc[4 + mi][g] = d;
            }
        __builtin_amdgcn_s_setprio(0);
        SBAR();

        asm volatile("s_waitcnt vmcnt(0)" ::: "memory");
        BAR();
    }

#pragma unroll
    for (int f = 0; f < 8; f++) {
        const int row = bm + (f >> 2)*128 + wm*64 + (f & 3)*16 + quad*4;
#pragma unroll
        for (int g = 0; g < 4; g++) {
            const int col = bn + (g >> 1)*128 + wn*32 + (g & 1)*16 + l16;
            const float bb = bias[col];
#pragma unroll
            for (int rr = 0; rr < 4; rr++)
                C[(size_t)(row + rr) * Nx + col] = acc[f][g][rr] + bb;
        }
    }
#undef STAGE_A2
#undef STAGE_B2
}

// ---------------------------------------------------------------------------
// FAVOR+ feature map for ONE batch (2048 blocks, 64 rows each) — proven R4.
// ---------------------------------------------------------------------------
__global__ __launch_bounds__(256) void favor_features_kernel(
    const float* __restrict__ qkvb, const float* __restrict__ proj,
    float* __restrict__ qp, float* __restrict__ kp)
{
    __shared__ float  projT[64*64];
    __shared__ float4 dnbuf[4][64];
    const int t = threadIdx.x;
    const int wave = t >> 6, lane = t & 63;
    const int part = blockIdx.y;
    float* outp = (part == 0) ? qp : kp;

    for (int i = t; i < 4096; i += 256)
        projT[(i & 63) * 64 + (i >> 6)] = proj[i];
    __syncthreads();

    const int h = blockIdx.x >> 6;
    const int n0 = (blockIdx.x & 63) * 64;
    const float* src = qkvb + part * D_ + h * HD_ + lane;

    for (int iter = 0; iter < 4; iter++) {
        const int n = n0 + iter * 16 + wave * 4;
        float v0 = src[(size_t)(n+0) * TD_];
        float v1 = src[(size_t)(n+1) * TD_];
        float v2 = src[(size_t)(n+2) * TD_];
        float v3 = src[(size_t)(n+3) * TD_];
        float4 dn = make_float4(v0*0.125f, v1*0.125f, v2*0.125f, v3*0.125f);
        dnbuf[wave][lane] = dn;
        float s0 = dn.x*dn.x, s1 = dn.y*dn.y, s2 = dn.z*dn.z, s3 = dn.w*dn.w;
#pragma unroll
        for (int off = 32; off >= 1; off >>= 1) {
            s0 += __shfl_xor(s0, off, 64);
            s1 += __shfl_xor(s1, off, 64);
            s2 += __shfl_xor(s2, off, 64);
            s3 += __shfl_xor(s3, off, 64);
        }
        float c0 = -0.5f*s0, c1 = -0.5f*s1, c2 = -0.5f*s2, c3 = -0.5f*s3;
#pragma unroll
        for (int d = 0; d < 64; d++) {
            float p = projT[d*64 + lane];
            float4 q = dnbuf[wave][d];
            c0 = fmaf(q.x, p, c0);
            c1 = fmaf(q.y, p, c1);
            c2 = fmaf(q.z, p, c2);
            c3 = fmaf(q.w, p, c3);
        }
        float m0 = c0, m1 = c1, m2 = c2, m3 = c3;
#pragma unroll
        for (int off = 32; off >= 1; off >>= 1) {
            m0 = fmaxf(m0, __shfl_xor(m0, off, 64));
            m1 = fmaxf(m1, __shfl_xor(m1, off, 64));
            m2 = fmaxf(m2, __shfl_xor(m2, off, 64));
            m3 = fmaxf(m3, __shfl_xor(m3, off, 64));
        }
        float r0 = expf(c0 - m0) * 0.125f + EPS_;
        float r1 = expf(c1 - m1) * 0.125f + EPS_;
        float r2 = expf(c2 - m2) * 0.125f + EPS_;
        float r3 = expf(c3 - m3) * 0.125f + EPS_;
        size_t orow = ((size_t)h * N_ + n) * 64 + lane;
        outp[orow]       = r0;
        outp[orow + 64]  = r1;
        outp[orow + 128] = r2;
        outp[orow + 192] = r3;
    }
}

// ---------------------------------------------------------------------------
// kv stage 1: per (h, n-chunk of 128) partial sums, no atomics — proven R4.
// ---------------------------------------------------------------------------
__global__ __launch_bounds__(256) void kv_partial_kernel(
    const float* __restrict__ qkvb, const float* __restrict__ kp,
    float* __restrict__ kvpart, float* __restrict__ kspart)
{
    const int t = threadIdx.x;
    const int h = blockIdx.x;
    const int c = blockIdx.y;
    const int n0 = c * 128;
    const int m0 = (t & 15) * 4;
    const int v0 = (t >> 4) * 4;

    const float* kpsrc = kp + ((size_t)h * N_ + n0) * 64 + m0;
    const float* vsrc  = qkvb + (size_t)n0 * TD_ + 2 * D_ + h * HD_ + v0;

    float acc[4][4];
#pragma unroll
    for (int i = 0; i < 4; i++)
#pragma unroll
        for (int j = 0; j < 4; j++) acc[i][j] = 0.f;
    float ks[4] = {0.f, 0.f, 0.f, 0.f};

#pragma unroll 4
    for (int n = 0; n < 128; n++) {
        float4 kq = *(const float4*)(kpsrc + (size_t)n * 64);
        float4 vq = *(const float4*)(vsrc  + (size_t)n * TD_);
        acc[0][0] = fmaf(kq.x, vq.x, acc[0][0]);
        acc[0][1] = fmaf(kq.x, vq.y, acc[0][1]);
        acc[0][2] = fmaf(kq.x, vq.z, acc[0][2]);
        acc[0][3] = fmaf(kq.x, vq.w, acc[0][3]);
        acc[1][0] = fmaf(kq.y, vq.x, acc[1][0]);
        acc[1][1] = fmaf(kq.y, vq.y, acc[1][1]);
        acc[1][2] = fmaf(kq.y, vq.z, acc[1][2]);
        acc[1][3] = fmaf(kq.y, vq.w, acc[1][3]);
        acc[2][0] = fmaf(kq.z, vq.x, acc[2][0]);
        acc[2][1] = fmaf(kq.z, vq.y, acc[2][1]);
        acc[2][2] = fmaf(kq.z, vq.z, acc[2][2]);
        acc[2][3] = fmaf(kq.z, vq.w, acc[2][3]);
        acc[3][0] = fmaf(kq.w, vq.x, acc[3][0]);
        acc[3][1] = fmaf(kq.w, vq.y, acc[3][1]);
        acc[3][2] = fmaf(kq.w, vq.z, acc[3][2]);
        acc[3][3] = fmaf(kq.w, vq.w, acc[3][3]);
        if (v0 == 0) {
            ks[0] += kq.x; ks[1] += kq.y; ks[2] += kq.z; ks[3] += kq.w;
        }
    }

    float* kvp = kvpart + (((size_t)h * 32 + c) * 4096) + m0 * 64 + v0;
#pragma unroll
    for (int i = 0; i < 4; i++)
        *(float4*)(kvp + i * 64) = make_float4(acc[i][0], acc[i][1], acc[i][2], acc[i][3]);

    if (v0 == 0) {
        float* ksp = kspart + ((size_t)h * 32 + c) * 64 + m0;
        *(float4*)ksp = make_float4(ks[0], ks[1], ks[2], ks[3]);
    }
}

// ---------------------------------------------------------------------------
// kv stage 2: reduce 32 chunk-partials -> kv[h][4096], ksum[h][64]
// grid (16,4) — proven R4.
// ---------------------------------------------------------------------------
__global__ __launch_bounds__(256) void kv_reduce_kernel(
    const float* __restrict__ kvpart, const float* __restrict__ kspart,
    float* __restrict__ kv, float* __restrict__ ksum)
{
    const int t = threadIdx.x;
    const int h = blockIdx.x;
    const int e0 = (blockIdx.y * 256 + t) * 4;

    float4 s = make_float4(0.f, 0.f, 0.f, 0.f);
    float kss = 0.f;
    const bool doks = (blockIdx.y == 0) && (t < 64);

    for (int c = 0; c < 32; c++) {
        float4 x = *(const float4*)(kvpart + (((size_t)h * 32 + c) * 4096) + e0);
        s.x += x.x; s.y += x.y; s.z += x.z; s.w += x.w;
        if (doks) kss += kspart[((size_t)h * 32 + c) * 64 + t];
    }

    *(float4*)(kv + (size_t)h * 4096 + e0) = s;
    if (doks) ksum[h * 64 + t] = kss;
}

// ---------------------------------------------------------------------------
// out[h,n,v] = (sum_m qp*kv) / (sum_m qp*ksum + eps) -> hi/lo bf16
// ---------------------------------------------------------------------------
__global__ __launch_bounds__(256) void out_kernel(
    const float* __restrict__ qp, const float* __restrict__ kv,
    const float* __restrict__ ksum, ushort* __restrict__ attn_hi,
    ushort* __restrict__ attn_lo)
{
    __shared__ float  kvs[4096];
    __shared__ float  kss[64];
    __shared__ float4 qbuf[4][64];
    const int t = threadIdx.x, lane = t & 63, wave = t >> 6;
    const int h = blockIdx.x;
    const int n0 = blockIdx.y * 64;

    for (int i = t; i < 4096; i += 256) kvs[i] = kv[(size_t)h * 4096 + i];
    if (t < 64) kss[t] = ksum[h * 64 + t];
    __syncthreads();

    const float* qsrc = qp + (size_t)h * N_ * 64 + lane;
    const size_t dbase = h * HD_ + lane;

    for (int iter = 0; iter < 4; iter++) {
        const int n = n0 + iter * 16 + wave * 4;
        float q0 = qsrc[(size_t)(n+0) * 64];
        float q1 = qsrc[(size_t)(n+1) * 64];
        float q2 = qsrc[(size_t)(n+2) * 64];
        float q3 = qsrc[(size_t)(n+3) * 64];
        qbuf[wave][lane] = make_float4(q0, q1, q2, q3);
        float t0 = q0 * kss[lane], t1 = q1 * kss[lane];
        float t2 = q2 * kss[lane], t3 = q3 * kss[lane];
#pragma unroll
        for (int off = 32; off >= 1; off >>= 1) {
            t0 += __shfl_xor(t0, off, 64);
            t1 += __shfl_xor(t1, off, 64);
            t2 += __shfl_xor(t2, off, 64);
            t3 += __shfl_xor(t3, off, 64);
        }
        float a0 = 0.f, a1 = 0.f, a2 = 0.f, a3 = 0.f;
#pragma unroll
        for (int m = 0; m < 64; m++) {
            float kvv = kvs[m*64 + lane];
            float4 q = qbuf[wave][m];
            a0 = fmaf(q.x, kvv, a0);
            a1 = fmaf(q.y, kvv, a1);
            a2 = fmaf(q.z, kvv, a2);
            a3 = fmaf(q.w, kvv, a3);
        }
        float r[4];
        r[0] = a0 / (t0 + EPS_); r[1] = a1 / (t1 + EPS_);
        r[2] = a2 / (t2 + EPS_); r[3] = a3 / (t3 + EPS_);
#pragma unroll
        for (int i = 0; i < 4; i++) {
            uint32 bits = __float_as_uint(r[i]);
            float lof = r[i] - __uint_as_float(bits & 0xFFFF0000u);
            size_t idx = (size_t)(n + i) * D_ + dbase;
            attn_hi[idx] = (ushort)(bits >> 16);
            attn_lo[idx] = (ushort)(__float_as_uint(lof) >> 16);
        }
    }
}

// ---------------------------------------------------------------------------
extern "C" void kernel_launch(void* const* d_in, const int* in_sizes, int n_in,
                              void* d_out, int out_size, void* d_ws, size_t ws_size,
                              hipStream_t stream)
{
    const float* x      = (const float*)d_in[0];   // [4,4096,1024]
    const float* qkv_w  = (const float*)d_in[1];   // [3072,1024]
    const float* qkv_b  = (const float*)d_in[2];   // [3072]
    const float* proj_w = (const float*)d_in[3];   // [1024,1024]
    const float* proj_b = (const float*)d_in[4];   // [1024]
    const float* pm     = (const float*)d_in[5];   // [64,64]
    float* out = (float*)d_out;                    // [4,4096,1024] fp32
    float* ws  = (float*)d_ws;

    const bool tierA = ws_size >= 327553024ULL;   // batched QKV + batched proj
    const bool tierB = ws_size >= 176558080ULL;   // per-batch QKV + batched proj (proven R4)

    if (tierA) {
        float* qkvbA  = ws;                          // 50,331,648 f
        float* qp     = qkvbA + 50331648;            //  4,194,304 f
        float* kp     = qp + 4194304;                //  4,194,304 f
        float* kvb    = kp + 4194304;                //     65,536 f
        float* ksum   = kvb + 65536;                 //      1,024 f
        float* kvpart = ksum + 1024;                 //  2,097,152 f
        float* kspart = kvpart + 2097152;            //     32,768 f
        float* axw    = kspart + 32768;              // 16,777,216 f (xw then attn)
        float* wsplit = axw + 16777216;              //  4,194,304 f

        ushort* xw_hi    = (ushort*)axw;
        ushort* xw_lo    = xw_hi + 16777216;
        ushort* attn_hi  = xw_hi;                    // alias: xw dead after GEMM1
        ushort* attn_lo  = xw_lo;
        ushort* qkvw_hi  = (ushort*)wsplit;
        ushort* qkvw_lo  = qkvw_hi + 3145728;
        ushort* projw_hi = qkvw_lo + 3145728;
        ushort* projw_lo = projw_hi + 1048576;

        split_kernel<<<1536, 256, 0, stream>>>(qkv_w, qkvw_hi, qkvw_lo, TD_*D_);
        split_kernel<<<512,  256, 0, stream>>>(proj_w, projw_hi, projw_lo, D_*D_);
        split_kernel<<<8192, 256, 0, stream>>>(x, xw_hi, xw_lo, B_*N_*D_);

        gemm256_pipe<<<dim3(12, 64), 512, 0, stream>>>(
            xw_hi, xw_lo, qkvw_hi, qkvw_lo, qkv_b, qkvbA, TD_, D_);

        for (int b = 0; b < B_; b++) {
            const float* qkvb = qkvbA + (size_t)b * N_ * TD_;
            favor_features_kernel<<<dim3(1024, 2), 256, 0, stream>>>(qkvb, pm, qp, kp);
            kv_partial_kernel<<<dim3(16, 32), 256, 0, stream>>>(qkvb, kp, kvpart, kspart);
            kv_reduce_kernel<<<dim3(16, 4), 256, 0, stream>>>(kvpart, kspart, kvb, ksum);
            out_kernel<<<dim3(16, 64), 256, 0, stream>>>(qp, kvb, ksum,
                attn_hi + (size_t)b * N_ * D_, attn_lo + (size_t)b * N_ * D_);
        }

        gemm256_pipe<<<dim3(4, 64), 512, 0, stream>>>(
            attn_hi, attn_lo, projw_hi, projw_lo, proj_b, out, D_, D_);
    } else if (tierB) {
        // per-batch QKV GEMM, batched proj GEMM (dedicated attnA) — R4 layout
        float* qkvb   = ws;                        // 12,582,912 f
        float* qp     = ws + 12582912;             //  4,194,304 f (xw aliases)
        float* kp     = qp + 4194304;              //  4,194,304 f
        float* kvb    = kp + 4194304;              //     65,536 f
        float* ksum   = kvb + 65536;               //      1,024 f
        float* kvpart = ksum + 1024;               //  2,097,152 f
        float* kspart = kvpart + 2097152;          //     32,768 f
        float* wsplit = kspart + 32768;            //  4,194,304 f
        float* attnA  = wsplit + 4194304;          // 16,777,216 f
        // total 44,139,520 f = 176,558,080 B

        ushort* xw_hi    = (ushort*)qp;
        ushort* xw_lo    = xw_hi + 4194304;
        ushort* qkvw_hi  = (ushort*)wsplit;
        ushort* qkvw_lo  = qkvw_hi + 3145728;
        ushort* projw_hi = qkvw_lo + 3145728;
        ushort* projw_lo = projw_hi + 1048576;
        ushort* attnA_hi = (ushort*)attnA;         // [16384 x 1024]
        ushort* attnA_lo = attnA_hi + 16777216;

        split_kernel<<<1536, 256, 0, stream>>>(qkv_w, qkvw_hi, qkvw_lo, TD_*D_);
        split_kernel<<<512,  256, 0, stream>>>(proj_w, projw_hi, projw_lo, D_*D_);

        for (int b = 0; b < B_; b++) {
            const float* xb = x + (size_t)b * N_ * D_;
            split_kernel<<<2048, 256, 0, stream>>>(xb, xw_hi, xw_lo, N_*D_);
            gemm256_pipe<<<dim3(12, 16), 512, 0, stream>>>(
                xw_hi, xw_lo, qkvw_hi, qkvw_lo, qkv_b, qkvb, TD_, D_);
            favor_features_kernel<<<dim3(1024, 2), 256, 0, stream>>>(qkvb, pm, qp, kp);
            kv_partial_kernel<<<dim3(16, 32), 256, 0, stream>>>(qkvb, kp, kvpart, kspart);
            kv_reduce_kernel<<<dim3(16, 4), 256, 0, stream>>>(kvpart, kspart, kvb, ksum);
            out_kernel<<<dim3(16, 64), 256, 0, stream>>>(qp, kvb, ksum,
                attnA_hi + (size_t)b * N_ * D_, attnA_lo + (size_t)b * N_ * D_);
        }

        gemm256_pipe<<<dim3(4, 64), 512, 0, stream>>>(
            attnA_hi, attnA_lo, projw_hi, projw_lo, proj_b, out, D_, D_);
    } else {
        // tier C: per-batch everything (~109.5 MB) — original proven layout
        float* qkvb   = ws;                        // 12,582,912 f
        float* qpreg  = ws + 12582912;             //  4,194,304 f
        float* kpreg  = qpreg + 4194304;           //  4,194,304 f
        float* kvb    = kpreg + 4194304;           //     65,536 f
        float* ksum   = kvb + 65536;               //      1,024 f
        float* kvpart = ksum + 1024;               //  2,097,152 f
        float* kspart = kvpart + 2097152;          //     32,768 f
        float* wsplit = kspart + 32768;            //  4,194,304 f

        ushort* xw_hi   = (ushort*)qpreg;
        ushort* xw_lo   = xw_hi + 4194304;
        float*  qp      = qpreg;
        float*  kp      = kpreg;
        ushort* attn_hi = (ushort*)kpreg;          // kp dead before out writes
        ushort* attn_lo = attn_hi + 4194304;
        ushort* qkvw_hi = (ushort*)wsplit;
        ushort* qkvw_lo = qkvw_hi + 3145728;
        ushort* projw_hi= qkvw_lo + 3145728;
        ushort* projw_lo= projw_hi + 1048576;

        split_kernel<<<TD_*D_/2048, 256, 0, stream>>>(qkv_w, qkvw_hi, qkvw_lo, TD_*D_);
        split_kernel<<<D_*D_/2048,  256, 0, stream>>>(proj_w, projw_hi, projw_lo, D_*D_);

        for (int b = 0; b < B_; b++) {
            const float* xb = x + (size_t)b * N_ * D_;
            float* outb = out + (size_t)b * N_ * D_;

            split_kernel<<<N_*D_/2048, 256, 0, stream>>>(xb, xw_hi, xw_lo, N_*D_);

            gemm256_pipe<<<dim3(12, 16), 512, 0, stream>>>(
                xw_hi, xw_lo, qkvw_hi, qkvw_lo, qkv_b, qkvb, TD_, D_);

            favor_features_kernel<<<dim3(1024, 2), 256, 0, stream>>>(qkvb, pm, qp, kp);
            kv_partial_kernel<<<dim3(16, 32), 256, 0, stream>>>(qkvb, kp, kvpart, kspart);
            kv_reduce_kernel<<<dim3(16, 4), 256, 0, stream>>>(kvpart, kspart, kvb, ksum);

            out_kernel<<<dim3(16, 64), 256, 0, stream>>>(qp, kvb, ksum, attn_hi, attn_lo);

            dim3 g5(D_ / 128, N_ / 128);
            gemm_presplit_nt_bias<<<g5, 256, 0, stream>>>(
                attn_hi, attn_lo, projw_hi, projw_lo, proj_b, outb, D_, D_);
        }
    }
}